// Round 9
// baseline (39.079 us; speedup 1.0000x reference)
//
#include <hip/hip_runtime.h>
#include <hip/hip_bf16.h>
#include <math.h>

#define N_NODES 2048
#define FIN 128
#define FOUT 64
#define BS 8
#define ALPHA 0.2f

typedef __attribute__((ext_vector_type(8))) short short8v;
typedef __attribute__((ext_vector_type(4))) float f32x4;

__device__ __forceinline__ short f2bf_s(float f) {
  unsigned u = __float_as_uint(f);
  unsigned r = (u + 0x7FFFu + ((u >> 16) & 1u)) >> 16;   // RNE
  return (short)r;
}
__device__ __forceinline__ float bf2f(short s) {
  return __uint_as_float(((unsigned)(unsigned short)s) << 16);
}
__device__ __forceinline__ unsigned int pack2bf(float a, float b) {
  __hip_bfloat162 t = __float22bfloat162_rn(make_float2(a, b));
  unsigned int r;
  __builtin_memcpy(&r, &t, 4);
  return r;
}
__device__ __forceinline__ float elu_f(float v) {
  return v > 0.f ? v : expm1f(v);
}

// ---------------- gat_prep: MFMA h + s1/s2 + hp pack + mask pack --------------
// 1024 blocks x 256 threads (4 waves). Block: b = bx>>7, 16-row tile i0.
// Wave w = column tile ct=w. h = 3-term hi/lo MFMA (~fp32 accuracy).
// adj loads hoisted to registers up-front so they overlap the W/x conversion work.
__global__ __launch_bounds__(256, 4) void gat_prep(const float* __restrict__ x,
                                                   const int* __restrict__ adj,
                                                   const float* __restrict__ W,
                                                   const float* __restrict__ a,
                                                   short* __restrict__ hp,
                                                   float* __restrict__ s1,
                                                   float* __restrict__ s2,
                                                   unsigned int* __restrict__ mask32) {
  const int bx = blockIdx.x;            // 0..1023
  const int b = bx >> 7;
  const int t16 = bx & 127;
  const int i0 = t16 * 16;
  const int w = threadIdx.x >> 6, lane = threadIdx.x & 63;
  const int kg = lane >> 4, rl = lane & 15;

  __shared__ float h_lds[16][68];

  // ---- issue adj loads first (16 outstanding, consumed later) ----
  const int mrow_id = 2 * bx + (w >> 1);
  const int* ar = adj + (long long)mrow_id * N_NODES + (w & 1) * 1024;
  int mreg[16];
  #pragma unroll
  for (int c = 0; c < 16; ++c) mreg[c] = ar[c * 64 + lane];

  // ---- W fragments for this wave's ct = w ----
  short8v bh[4], bl[4];
  #pragma unroll
  for (int ks = 0; ks < 4; ++ks) {
    #pragma unroll
    for (int e = 0; e < 8; ++e) {
      const float wv = W[(ks * 32 + kg * 8 + e) * FOUT + w * 16 + rl];
      const short hsh = f2bf_s(wv);
      bh[ks][e] = hsh;
      bl[ks][e] = f2bf_s(wv - bf2f(hsh));
    }
  }

  // ---- h tile via 3-term MFMA: A-frag lane (kg,rl): row=rl, k=kg*8+e ----
  const float* xB = x + ((long long)b * N_NODES + i0 + rl) * FIN + kg * 8;
  f32x4 ahh = {0.f, 0.f, 0.f, 0.f};
  f32x4 ahl = {0.f, 0.f, 0.f, 0.f};
  f32x4 alh = {0.f, 0.f, 0.f, 0.f};
  #pragma unroll
  for (int ks = 0; ks < 4; ++ks) {
    const float4 xa = *reinterpret_cast<const float4*>(xB + ks * 32);
    const float4 xb = *reinterpret_cast<const float4*>(xB + ks * 32 + 4);
    const float xf[8] = {xa.x, xa.y, xa.z, xa.w, xb.x, xb.y, xb.z, xb.w};
    short8v xh, xl;
    #pragma unroll
    for (int e = 0; e < 8; ++e) {
      const short hsh = f2bf_s(xf[e]);
      xh[e] = hsh;
      xl[e] = f2bf_s(xf[e] - bf2f(hsh));
    }
    ahh = __builtin_amdgcn_mfma_f32_16x16x32_bf16(xh, bh[ks], ahh, 0, 0, 0);
    ahl = __builtin_amdgcn_mfma_f32_16x16x32_bf16(xh, bl[ks], ahl, 0, 0, 0);
    alh = __builtin_amdgcn_mfma_f32_16x16x32_bf16(xl, bh[ks], alh, 0, 0, 0);
  }
  const f32x4 acc = (ahh + ahl) + alh;
  #pragma unroll
  for (int r = 0; r < 4; ++r)
    h_lds[kg * 4 + r][w * 16 + rl] = acc[r];

  // ---- mask ballots on the prefetched regs ----
  {
    unsigned int* mw = mask32 + mrow_id * 64 + (w & 1) * 32;
    #pragma unroll
    for (int c = 0; c < 16; ++c) {
      const unsigned long long bal = __ballot(mreg[c] > 0);
      if (lane == 0) mw[2 * c] = (unsigned int)bal;
      if (lane == 1) mw[2 * c + 1] = (unsigned int)(bal >> 32);
    }
  }

  __syncthreads();

  // ---- s1/s2: wave w reduces rows 4w..4w+3 ----
  {
    const float a1v = a[lane], a2v = a[FOUT + lane];
    #pragma unroll
    for (int rr = 0; rr < 4; ++rr) {
      const float hv = h_lds[4 * w + rr][lane];
      float p = hv * a1v, q = hv * a2v;
      #pragma unroll
      for (int off = 32; off > 0; off >>= 1) {
        p += __shfl_xor(p, off);
        q += __shfl_xor(q, off);
      }
      if (lane == 0) {
        s1[(long long)b * N_NODES + i0 + 4 * w + rr] = p;
        s2[(long long)b * N_NODES + i0 + 4 * w + rr] = q;
      }
    }
  }

  // ---- hp pack: wave w = ct; this 16-row tile is k-half kh of hp tile jt ----
  if (lane < 32) {
    const int jt = t16 >> 1, kh = t16 & 1;
    const int kgl = lane >> 4, col = lane & 15;
    union { short8v v; unsigned int u[4]; } o;
    #pragma unroll
    for (int i = 0; i < 4; ++i)
      o.u[i] = pack2bf(h_lds[kgl * 8 + 2 * i][w * 16 + col],
                       h_lds[kgl * 8 + 2 * i + 1][w * 16 + col]);
    *reinterpret_cast<short8v*>(
        hp + (((long long)(b * 256 + jt * 4 + w)) * 64 + (kh * 2 + kgl) * 16 + col) * 8) = o.v;
  }
}

// ---------------- gat_attn: 32 rows/block, 2 A-frags/wave, split-j partials ---
// Grid (64 i-tiles, 2 j-halves, 8 b) = 1024 blocks x 512 thr (4 blk/CU, 32 w/CU).
// Writes unnormalized partial C and partial row-sum to ws; finish kernel divides.
__global__ __launch_bounds__(512) void gat_attn(const unsigned int* __restrict__ mask32,
                                                const short* __restrict__ hp,
                                                const float* __restrict__ s1g,
                                                const float* __restrict__ s2g,
                                                float* __restrict__ part,
                                                float* __restrict__ psum) {
  const int b = blockIdx.z;
  const int jh = blockIdx.y;
  const int i0 = blockIdx.x * 32;
  const int t = threadIdx.x;
  const int w = t >> 6, lane = t & 63;
  const int kg = lane >> 4, rl = lane & 15;

  __shared__ float red[8][16 * 64];   // 32 KB
  __shared__ float ps[8][16];

  const float s1v1 = s1g[b * N_NODES + i0 + rl];
  const float s1v2 = s1g[b * N_NODES + i0 + 16 + rl];
  const float* s2B = s2g + b * N_NODES;
  const unsigned int* mrow1 = mask32 + (i0 + rl) * 64;
  const unsigned int* mrow2 = mask32 + (i0 + 16 + rl) * 64;
  const short8v* hpB = reinterpret_cast<const short8v*>(hp) + (long long)b * 16384;

  f32x4 a10 = {0.f, 0.f, 0.f, 0.f}, a11 = {0.f, 0.f, 0.f, 0.f};
  f32x4 a12 = {0.f, 0.f, 0.f, 0.f}, a13 = {0.f, 0.f, 0.f, 0.f};
  f32x4 a20 = {0.f, 0.f, 0.f, 0.f}, a21 = {0.f, 0.f, 0.f, 0.f};
  f32x4 a22 = {0.f, 0.f, 0.f, 0.f}, a23 = {0.f, 0.f, 0.f, 0.f};
  f32x4 aS1 = {0.f, 0.f, 0.f, 0.f}, aS2 = {0.f, 0.f, 0.f, 0.f};
  union { short8v v; unsigned int u[4]; } ones;
  #pragma unroll
  for (int i = 0; i < 4; ++i) ones.u[i] = 0x3F803F80u;

  const int jt_end = (jh + 1) * 32;
  for (int jt = jh * 32 + w; jt < jt_end; jt += 8) {
    const short8v* hpt = hpB + jt * 256;
    const short8v b0 = hpt[0 * 64 + lane];
    const short8v b1 = hpt[1 * 64 + lane];
    const short8v b2 = hpt[2 * 64 + lane];
    const short8v b3 = hpt[3 * 64 + lane];
    const float4 sa = *reinterpret_cast<const float4*>(s2B + jt * 32 + kg * 8);
    const float4 sb = *reinterpret_cast<const float4*>(s2B + jt * 32 + kg * 8 + 4);
    const unsigned int m1 = mrow1[jt] >> (kg * 8);
    const unsigned int m2 = mrow2[jt] >> (kg * 8);
    const float s2e[8] = {sa.x, sa.y, sa.z, sa.w, sb.x, sb.y, sb.z, sb.w};
    float p1[8], p2[8];
    #pragma unroll
    for (int e = 0; e < 8; e++) {
      float sc1 = s1v1 + s2e[e];
      float sc2 = s2e[e] + s1v2;
      sc1 = fmaxf(sc1, ALPHA * sc1);
      sc2 = fmaxf(sc2, ALPHA * sc2);
      p1[e] = ((m1 >> e) & 1u) ? __expf(sc1) : 0.f;
      p2[e] = ((m2 >> e) & 1u) ? __expf(sc2) : 0.f;
    }
    union { short8v v; unsigned int u[4]; } af1, af2;
    #pragma unroll
    for (int i = 0; i < 4; ++i) {
      af1.u[i] = pack2bf(p1[2 * i], p1[2 * i + 1]);
      af2.u[i] = pack2bf(p2[2 * i], p2[2 * i + 1]);
    }
    a10 = __builtin_amdgcn_mfma_f32_16x16x32_bf16(af1.v, b0, a10, 0, 0, 0);
    a20 = __builtin_amdgcn_mfma_f32_16x16x32_bf16(af2.v, b0, a20, 0, 0, 0);
    a11 = __builtin_amdgcn_mfma_f32_16x16x32_bf16(af1.v, b1, a11, 0, 0, 0);
    a21 = __builtin_amdgcn_mfma_f32_16x16x32_bf16(af2.v, b1, a21, 0, 0, 0);
    a12 = __builtin_amdgcn_mfma_f32_16x16x32_bf16(af1.v, b2, a12, 0, 0, 0);
    a22 = __builtin_amdgcn_mfma_f32_16x16x32_bf16(af2.v, b2, a22, 0, 0, 0);
    a13 = __builtin_amdgcn_mfma_f32_16x16x32_bf16(af1.v, b3, a13, 0, 0, 0);
    a23 = __builtin_amdgcn_mfma_f32_16x16x32_bf16(af2.v, b3, a23, 0, 0, 0);
    aS1 = __builtin_amdgcn_mfma_f32_16x16x32_bf16(af1.v, ones.v, aS1, 0, 0, 0);
    aS2 = __builtin_amdgcn_mfma_f32_16x16x32_bf16(af2.v, ones.v, aS2, 0, 0, 0);
  }

  float* partH = part + ((long long)jh * BS + b) * N_NODES * FOUT;
  float* psumH = psum + ((long long)jh * BS + b) * N_NODES;

  // ---- phase 1: rows i0..i0+15 ----
  #pragma unroll
  for (int r = 0; r < 4; r++) {
    red[w][(kg * 4 + r) * 64 + 0 * 16 + rl] = a10[r];
    red[w][(kg * 4 + r) * 64 + 1 * 16 + rl] = a11[r];
    red[w][(kg * 4 + r) * 64 + 2 * 16 + rl] = a12[r];
    red[w][(kg * 4 + r) * 64 + 3 * 16 + rl] = a13[r];
  }
  if (rl == 0) {
    #pragma unroll
    for (int r = 0; r < 4; r++) ps[w][kg * 4 + r] = aS1[r];
  }
  __syncthreads();
  {
    const int row = t >> 5;
    const int c2 = (t & 31) * 2;
    float den = 0.f, v0 = 0.f, v1 = 0.f;
    #pragma unroll
    for (int s = 0; s < 8; ++s) {
      den += ps[s][row];
      const float* rp = &red[s][row * 64 + c2];
      v0 += rp[0]; v1 += rp[1];
    }
    float2 ov; ov.x = v0; ov.y = v1;
    *reinterpret_cast<float2*>(partH + (long long)(i0 + row) * FOUT + c2) = ov;
    if (c2 == 0) psumH[i0 + row] = den;
  }
  __syncthreads();

  // ---- phase 2: rows i0+16..i0+31 ----
  #pragma unroll
  for (int r = 0; r < 4; r++) {
    red[w][(kg * 4 + r) * 64 + 0 * 16 + rl] = a20[r];
    red[w][(kg * 4 + r) * 64 + 1 * 16 + rl] = a21[r];
    red[w][(kg * 4 + r) * 64 + 2 * 16 + rl] = a22[r];
    red[w][(kg * 4 + r) * 64 + 3 * 16 + rl] = a23[r];
  }
  if (rl == 0) {
    #pragma unroll
    for (int r = 0; r < 4; r++) ps[w][kg * 4 + r] = aS2[r];
  }
  __syncthreads();
  {
    const int row = t >> 5;
    const int c2 = (t & 31) * 2;
    float den = 0.f, v0 = 0.f, v1 = 0.f;
    #pragma unroll
    for (int s = 0; s < 8; ++s) {
      den += ps[s][row];
      const float* rp = &red[s][row * 64 + c2];
      v0 += rp[0]; v1 += rp[1];
    }
    float2 ov; ov.x = v0; ov.y = v1;
    *reinterpret_cast<float2*>(partH + (long long)(i0 + 16 + row) * FOUT + c2) = ov;
    if (c2 == 0) psumH[i0 + 16 + row] = den;
  }
}

// ---------------- gat_finish: out = elu((c0+c1)/(d0+d1)) ---------------------
__global__ __launch_bounds__(256) void gat_finish(const float* __restrict__ part,
                                                  const float* __restrict__ psum,
                                                  float* __restrict__ out) {
  const int g = blockIdx.x * 256 + threadIdx.x;   // 0..262143 (float4 units)
  const int row = g >> 4;                          // b*N + i
  const int c4 = (g & 15) * 4;
  const float den = psum[row] + psum[BS * N_NODES + row];
  const float inv = 1.0f / den;
  const float4 c0 = *reinterpret_cast<const float4*>(part + ((long long)row << 6) + c4);
  const float4 c1 = *reinterpret_cast<const float4*>(part + ((long long)(BS * N_NODES + row) << 6) + c4);
  float4 ov;
  ov.x = elu_f((c0.x + c1.x) * inv);
  ov.y = elu_f((c0.y + c1.y) * inv);
  ov.z = elu_f((c0.z + c1.z) * inv);
  ov.w = elu_f((c0.w + c1.w) * inv);
  *reinterpret_cast<float4*>(out + ((long long)row << 6) + c4) = ov;
}

extern "C" void kernel_launch(void* const* d_in, const int* in_sizes, int n_in,
                              void* d_out, int out_size, void* d_ws, size_t ws_size,
                              hipStream_t stream) {
  const float* x   = (const float*)d_in[0];
  const int*   adj = (const int*)d_in[1];
  const float* W   = (const float*)d_in[2];
  const float* a   = (const float*)d_in[3];
  float* out = (float*)d_out;

  short* hp = (short*)d_ws;                                        // 2 MB
  float* s1 = (float*)(hp + (long long)BS * N_NODES * FOUT);       // 64 KB
  float* s2 = s1 + BS * N_NODES;                                   // 64 KB
  unsigned int* mask32 = (unsigned int*)(s2 + BS * N_NODES);       // 512 KB
  float* part = (float*)(mask32 + N_NODES * 64);                   // 2 * 4 MB
  float* psum = part + 2LL * BS * N_NODES * FOUT;                  // 2 * 64 KB

  gat_prep<<<1024, 256, 0, stream>>>(x, adj, W, a, hp, s1, s2, mask32);
  gat_attn<<<dim3(N_NODES / 32, 2, BS), 512, 0, stream>>>(mask32, hp, s1, s2, part, psum);
  gat_finish<<<BS * N_NODES * FOUT / 4 / 256, 256, 0, stream>>>(part, psum, out);
}